// Round 10
// baseline (221.051 us; speedup 1.0000x reference)
//
#include <hip/hip_runtime.h>

typedef unsigned short u16;
typedef __attribute__((ext_vector_type(8))) short bf16x8;
typedef __attribute__((ext_vector_type(4))) float f32x4;

#define B_N 4
#define SQ 2048
#define SKV 2048
#define DE 1024
#define DC 768
#define DA 1024
#define NH 16
#define DH 64
#define MTOT (B_N * SQ) /* 8192 */
#define LOG2E 1.44269504088896f

__device__ __forceinline__ u16 f2bf(float f) {
    unsigned u = __float_as_uint(f);
    u += 0x7FFF + ((u >> 16) & 1);
    return (u16)(u >> 16);
}
__device__ __forceinline__ f32x4 mfma_bf16(bf16x8 a, bf16x8 b, f32x4 c) {
    return __builtin_amdgcn_mfma_f32_16x16x32_bf16(a, b, c, 0, 0, 0);
}
__device__ __forceinline__ void gload16(const void* g, void* l) {
    __builtin_amdgcn_global_load_lds(
        (const __attribute__((address_space(1))) unsigned int*)g,
        (__attribute__((address_space(3))) unsigned int*)l, 16, 0, 0);
}
__device__ __forceinline__ unsigned cvtpk(float a, float b) {
    unsigned r;
    asm("v_cvt_pk_bf16_f32 %0, %1, %2" : "=v"(r) : "v"(a), "v"(b));
    return r;
}

// ---------------- fp32 -> bf16 row-major convert (8 elems/thread)
__global__ __launch_bounds__(256) void k_cvt(const float* __restrict__ s, u16* __restrict__ d) {
    size_t i = ((size_t)blockIdx.x * 256 + threadIdx.x) * 8;
    float4 v0 = *(const float4*)(s + i);
    float4 v1 = *(const float4*)(s + i + 4);
    uint4 u;
    u.x = cvtpk(v0.x, v0.y);
    u.y = cvtpk(v0.z, v0.w);
    u.z = cvtpk(v1.x, v1.y);
    u.w = cvtpk(v1.z, v1.w);
    *(uint4*)(d + i) = u;
}

// ---------------- transpose of a KxN f32 weight into N x K bf16 (optional scale)
__global__ __launch_bounds__(256) void k_tsplit(const float* __restrict__ W,
                                                u16* __restrict__ Th,
                                                int K, int N, float scale) {
    __shared__ float t[32][33];
    const int k0 = blockIdx.x * 32, n0 = blockIdx.y * 32;
    const int tx = threadIdx.x & 31, ty = threadIdx.x >> 5;
#pragma unroll
    for (int i = 0; i < 4; ++i)
        t[ty + 8 * i][tx] = W[(size_t)(k0 + ty + 8 * i) * N + (n0 + tx)];
    __syncthreads();
#pragma unroll
    for (int i = 0; i < 4; ++i) {
        float v = t[tx][ty + 8 * i] * scale;
        Th[(size_t)(n0 + ty + 8 * i) * K + (k0 + tx)] = f2bf(v);
    }
}

// ---------------- GEMM: C[M x 1024] = A[M x KTOT](bf16) @ B[1024 x KTOT](bf16)^T
// 128x128 tile, BK=64, 4 waves. Double-buffered LDS (attn-proven pattern):
// one __syncthreads per K-tile; prefetch t+1 right after the barrier; the
// compiler's vmcnt drain at the barrier fences buf[cur].
// EPI: 0 = fp32 C + bias; 3 = bf16 C + bias*bscale;
//      1 = K-tile (bf16, drow-permuted rows); 2 = V-tile (V^T bf16, natural kv)
template <int KTOT, int EPI>
__global__ __launch_bounds__(256) void k_gemm(const u16* __restrict__ Ab,
                                              const u16* __restrict__ Bb,
                                              const float* __restrict__ bias,
                                              float bscale,
                                              float* __restrict__ C,
                                              u16* __restrict__ Cb) {
    __shared__ u16 sA[2][128 * 64], sB[2][128 * 64];
    const int tid = threadIdx.x;
    const int lane = tid & 63, w = tid >> 6;
    const int wm = w >> 1, wn = w & 1;
    const int g = lane >> 4, r16 = lane & 15;
    const int m0 = blockIdx.x * 128, n0 = blockIdx.y * 128;
    const int xa = r16 & 7;
    const int NT = KTOT / 64;

    const f32x4 fzero = {0.f, 0.f, 0.f, 0.f};
    f32x4 acc[4][4];
#pragma unroll
    for (int i = 0; i < 4; ++i)
#pragma unroll
        for (int j = 0; j < 4; ++j) acc[i][j] = fzero;

    // prologue: stage tile 0 into buf 0
#pragma unroll
    for (int i = 0; i < 4; ++i) {
        int slot = tid + i * 256;
        int row = slot >> 3, cs = slot & 7;
        size_t off = (size_t)(m0 + row) * (KTOT * 2) + (size_t)((cs ^ (row & 7)) << 4);
        gload16((const char*)Ab + off, (char*)&sA[0][0] + slot * 16);
        size_t boff = (size_t)(n0 + row) * (KTOT * 2) + (size_t)((cs ^ (row & 7)) << 4);
        gload16((const char*)Bb + boff, (char*)&sB[0][0] + slot * 16);
    }

    for (int kt = 0; kt < NT; ++kt) {
        const int cur = kt & 1;
        __syncthreads();   // drains vmcnt: buf[cur] ready; buf[cur^1] free
        if (kt + 1 < NT) {
#pragma unroll
            for (int i = 0; i < 4; ++i) {
                int slot = tid + i * 256;
                int row = slot >> 3, cs = slot & 7;
                size_t off = (size_t)(m0 + row) * (KTOT * 2) + (size_t)(kt + 1) * 128 +
                             (size_t)((cs ^ (row & 7)) << 4);
                gload16((const char*)Ab + off, (char*)&sA[cur ^ 1][0] + slot * 16);
                size_t boff = (size_t)(n0 + row) * (KTOT * 2) + (size_t)(kt + 1) * 128 +
                              (size_t)((cs ^ (row & 7)) << 4);
                gload16((const char*)Bb + boff, (char*)&sB[cur ^ 1][0] + slot * 16);
            }
        }
        const char* pA = (const char*)&sA[cur][0];
        const char* pB = (const char*)&sB[cur][0];
        bf16x8 ah[4][2], bh[4][2];
#pragma unroll
        for (int f = 0; f < 4; ++f)
#pragma unroll
            for (int s = 0; s < 2; ++s) {
                const int ar = wm * 64 + f * 16 + r16;
                const int br = wn * 64 + f * 16 + r16;
                const int cb = ((s * 4 + g) ^ xa) << 4;
                ah[f][s] = *(const bf16x8*)(pA + ar * 128 + cb);
                bh[f][s] = *(const bf16x8*)(pB + br * 128 + cb);
            }
        __builtin_amdgcn_s_setprio(1);
#pragma unroll
        for (int s = 0; s < 2; ++s)
#pragma unroll
            for (int fm = 0; fm < 4; ++fm)
#pragma unroll
                for (int fn = 0; fn < 4; ++fn)
                    acc[fm][fn] = mfma_bf16(ah[fm][s], bh[fn][s], acc[fm][fn]);
        __builtin_amdgcn_s_setprio(0);
    }

#pragma unroll
    for (int fn = 0; fn < 4; ++fn) {
        const int col = n0 + wn * 64 + fn * 16 + r16;
        const float bv = bias[col] * bscale;
        const int h = col >> 6, dh = col & 63;
#pragma unroll
        for (int fm = 0; fm < 4; ++fm)
#pragma unroll
            for (int r = 0; r < 4; ++r) {
                const int row = m0 + wm * 64 + fm * 16 + g * 4 + r;
                const float v = acc[fm][fn][r] + bv;
                if constexpr (EPI == 0) {
                    C[(size_t)row * 1024 + col] = v;
                } else if constexpr (EPI == 3) {
                    Cb[(size_t)row * 1024 + col] = f2bf(v);
                } else {
                    const int b = row >> 11, kv = row & 2047;
                    const int t = kv >> 6, kvr = kv & 63;
                    const size_t tb = (size_t)((b * 16 + h) * 32 + t) * 8192;
                    if constexpr (EPI == 1) {
                        // K: drow-permuted rows, chunk-swizzled (round-7 verbatim)
                        const int drow = (kvr & 3) * 16 + (kvr >> 2);
                        Cb[tb + drow * 64 + (((dh >> 3) ^ (drow & 7)) << 3) + (dh & 7)] = f2bf(v);
                    } else {
                        // V^T: row dh, natural kv columns, chunk-swizzled (round-7 verbatim)
                        Cb[tb + 4096 + dh * 64 + (((kvr >> 3) ^ (dh & 7)) << 3) + (kvr & 7)] = f2bf(v);
                    }
                }
            }
    }
}

// ---------------- flash attention: round-7 verbatim structure (known good),
// with bf16 pre-scaled Q (0.125*log2e baked in) and exp2f instead of __expf.
__global__ __launch_bounds__(256, 2) void k_attn(const u16* __restrict__ Qb,
                                                 const u16* __restrict__ KV,
                                                 u16* __restrict__ Af) {
    __shared__ u16 sKV[2][8192];      // per buf: [Kh 4096 u16][Vh 4096 u16]
    __shared__ u16 Ps[4][64][64];     // per-wave P, 128B rows, XOR-swizzled
    const int lin = blockIdx.x;
    const int swz = (lin & 7) * 64 + (lin >> 3);   // XCD-aware (512 % 8 == 0)
    const int qt = swz & 7, bh = swz >> 3;
    const int b = bh >> 4, h = bh & 15;
    const int tid = threadIdx.x, lane = tid & 63, w = tid >> 6;
    const int g = lane >> 4, r16 = lane & 15;
    const int xk = (r16 & 7) << 4;
    const int qbase = qt * 256 + w * 64;

    // Q fragments: Qb = 0.125*log2e*(x@Wq+bq) bf16 — direct loads
    bf16x8 qh[4][2];
#pragma unroll
    for (int rf = 0; rf < 4; ++rf) {
        const size_t qrow = (size_t)(b * SQ + qbase + rf * 16 + r16);
#pragma unroll
        for (int s = 0; s < 2; ++s)
            qh[rf][s] = *(const bf16x8*)&Qb[qrow * DA + h * 64 + s * 32 + g * 8];
    }

    const f32x4 fzero = {0.f, 0.f, 0.f, 0.f};
    f32x4 oacc[4][4];
    f32x4 l_run[4];
#pragma unroll
    for (int rf = 0; rf < 4; ++rf) {
        l_run[rf] = fzero;
#pragma unroll
        for (int i = 0; i < 4; ++i) oacc[rf][i] = fzero;
    }

    char* pw = (char*)&Ps[w][0][0];
    const char* gb0 = (const char*)KV + (size_t)bh * 32 * 16384;

    // prologue: stage tile 0 into buf 0
#pragma unroll
    for (int i = 0; i < 4; ++i) {
        int c = w * 4 + i;
        gload16(gb0 + c * 1024 + lane * 16, (char*)&sKV[0][0] + c * 1024);
    }

    for (int t = 0; t < SKV / 64; ++t) {
        const int cur = t & 1;
        __syncthreads();   // drains vmcnt: buf[cur] ready; buf[cur^1] safe to overwrite
        {
            const char* gnext = gb0 + (size_t)((t + 1) & 31) * 16384;
            char* lnext = (char*)&sKV[cur ^ 1][0];
#pragma unroll
            for (int i = 0; i < 4; ++i) {
                int c = w * 4 + i;
                gload16(gnext + c * 1024 + lane * 16, lnext + c * 1024);
            }
        }
        const char* smb = (const char*)&sKV[cur][0];

        // hoisted K fragments
        bf16x8 kh[4][2];
#pragma unroll
        for (int f = 0; f < 4; ++f)
#pragma unroll
            for (int s = 0; s < 2; ++s)
                kh[f][s] = *(const bf16x8*)(smb + (f * 16 + r16) * 128 + ((s * 64 + g * 16) ^ xk));

#pragma unroll
        for (int rf = 0; rf < 4; ++rf) {
            f32x4 sacc[4];
#pragma unroll
            for (int f = 0; f < 4; ++f) sacc[f] = fzero;
            __builtin_amdgcn_s_setprio(1);
#pragma unroll
            for (int f = 0; f < 4; ++f)
#pragma unroll
                for (int s = 0; s < 2; ++s)
                    sacc[f] = mfma_bf16(qh[rf][s], kh[f][s], sacc[f]);
            __builtin_amdgcn_s_setprio(0);
#pragma unroll
            for (int r = 0; r < 4; ++r) {
                float p0 = exp2f(sacc[0][r]);
                float p1 = exp2f(sacc[1][r]);
                float p2 = exp2f(sacc[2][r]);
                float p3 = exp2f(sacc[3][r]);
                l_run[rf][r] += (p0 + p1) + (p2 + p3);
                int prow = rf * 16 + g * 4 + r;
                uint2 pk;
                pk.x = cvtpk(p0, p1);
                pk.y = cvtpk(p2, p3);
                *(uint2*)(pw + prow * 128 + ((r16 * 8) ^ ((prow & 7) << 4))) = pk;
            }
        }

        // PV: hoisted P A-fragments, transient V fragments (bf16 V)
        bf16x8 pa[4][2];
#pragma unroll
        for (int rf = 0; rf < 4; ++rf)
#pragma unroll
            for (int s = 0; s < 2; ++s)
                pa[rf][s] = *(const bf16x8*)(pw + (rf * 16 + r16) * 128 + ((s * 64 + g * 16) ^ xk));
#pragma unroll
        for (int fd = 0; fd < 4; ++fd)
#pragma unroll
            for (int s = 0; s < 2; ++s) {
                bf16x8 vh = *(const bf16x8*)(smb + 8192 + (fd * 16 + r16) * 128 + ((s * 64 + g * 16) ^ xk));
                __builtin_amdgcn_s_setprio(1);
#pragma unroll
                for (int rf = 0; rf < 4; ++rf)
                    oacc[rf][fd] = mfma_bf16(pa[rf][s], vh, oacc[rf][fd]);
                __builtin_amdgcn_s_setprio(0);
            }
    }

    // final cross-lane reduce of l (sum over the 16 lanes sharing each row)
#pragma unroll
    for (int rf = 0; rf < 4; ++rf)
#pragma unroll
        for (int x = 1; x < 16; x <<= 1)
#pragma unroll
            for (int r = 0; r < 4; ++r) l_run[rf][r] += __shfl_xor(l_run[rf][r], x);

#pragma unroll
    for (int rf = 0; rf < 4; ++rf) {
        float linv[4];
#pragma unroll
        for (int r = 0; r < 4; ++r) linv[r] = 1.0f / l_run[rf][r];
#pragma unroll
        for (int fd = 0; fd < 4; ++fd)
#pragma unroll
            for (int r = 0; r < 4; ++r) {
                int row = qbase + rf * 16 + g * 4 + r;
                Af[(size_t)(b * SQ + row) * DA + h * 64 + fd * 16 + r16] =
                    f2bf(oacc[rf][fd][r] * linv[r]);
            }
    }
}

extern "C" void kernel_launch(void* const* d_in, const int* in_sizes, int n_in,
                              void* d_out, int out_size, void* d_ws, size_t ws_size,
                              hipStream_t stream) {
    const float* x = (const float*)d_in[0];
    const float* y = (const float*)d_in[1];
    const float* Wq = (const float*)d_in[2];
    const float* bq = (const float*)d_in[3];
    const float* Wk = (const float*)d_in[4];
    const float* bk = (const float*)d_in[5];
    const float* Wv = (const float*)d_in[6];
    const float* bv = (const float*)d_in[7];
    const float* Wo = (const float*)d_in[8];
    const float* bo = (const float*)d_in[9];
    float* out = (float*)d_out;

    char* p = (char*)d_ws;
    u16* Qb = (u16*)p; p += (size_t)MTOT * DA * 2;
    u16* Af = (u16*)p; p += (size_t)MTOT * DA * 2;
    u16* xb = (u16*)p; p += (size_t)MTOT * DE * 2;
    u16* yb = (u16*)p; p += (size_t)MTOT * DC * 2;
    u16* KV = (u16*)p; p += (size_t)64 * 32 * 8192 * 2;  // 32 MB combined K/V tiles
    u16* wq = (u16*)p; p += (size_t)DE * DA * 2;
    u16* wk = (u16*)p; p += (size_t)DC * DA * 2;
    u16* wv = (u16*)p; p += (size_t)DC * DA * 2;
    u16* wo = (u16*)p; p += (size_t)DA * DE * 2;

    const float qs = 0.125f * LOG2E;

    k_cvt<<<MTOT * DE / 2048, 256, 0, stream>>>(x, xb);
    k_cvt<<<MTOT * DC / 2048, 256, 0, stream>>>(y, yb);

    k_tsplit<<<dim3(DE / 32, DA / 32), 256, 0, stream>>>(Wq, wq, DE, DA, qs);
    k_tsplit<<<dim3(DC / 32, DA / 32), 256, 0, stream>>>(Wk, wk, DC, DA, 1.0f);
    k_tsplit<<<dim3(DC / 32, DA / 32), 256, 0, stream>>>(Wv, wv, DC, DA, 1.0f);
    k_tsplit<<<dim3(DA / 32, DE / 32), 256, 0, stream>>>(Wo, wo, DA, DE, 1.0f);

    k_gemm<DE, 3><<<dim3(MTOT / 128, DA / 128), 256, 0, stream>>>(xb, wq, bq, qs, nullptr, Qb);
    k_gemm<DC, 1><<<dim3(MTOT / 128, DA / 128), 256, 0, stream>>>(yb, wk, bk, 1.0f, nullptr, KV);
    k_gemm<DC, 2><<<dim3(MTOT / 128, DA / 128), 256, 0, stream>>>(yb, wv, bv, 1.0f, nullptr, KV);

    k_attn<<<dim3(512), 256, 0, stream>>>(Qb, KV, Af);

    k_gemm<DA, 0><<<dim3(MTOT / 128, DE / 128), 256, 0, stream>>>(Af, wo, bo, 1.0f, out, nullptr);
}

// Round 11
// 192.653 us; speedup vs baseline: 1.1474x; 1.1474x over previous
//
#include <hip/hip_runtime.h>

typedef unsigned short u16;
typedef __attribute__((ext_vector_type(8))) short bf16x8;
typedef __attribute__((ext_vector_type(4))) float f32x4;

#define B_N 4
#define SQ 2048
#define SKV 2048
#define DE 1024
#define DC 768
#define DA 1024
#define NH 16
#define DH 64
#define MTOT (B_N * SQ) /* 8192 */
#define LOG2E 1.44269504088896f

__device__ __forceinline__ u16 f2bf(float f) {
    unsigned u = __float_as_uint(f);
    u += 0x7FFF + ((u >> 16) & 1);
    return (u16)(u >> 16);
}
__device__ __forceinline__ f32x4 mfma_bf16(bf16x8 a, bf16x8 b, f32x4 c) {
    return __builtin_amdgcn_mfma_f32_16x16x32_bf16(a, b, c, 0, 0, 0);
}
__device__ __forceinline__ void gload16(const void* g, void* l) {
    __builtin_amdgcn_global_load_lds(
        (const __attribute__((address_space(1))) unsigned int*)g,
        (__attribute__((address_space(3))) unsigned int*)l, 16, 0, 0);
}
__device__ __forceinline__ unsigned cvtpk(float a, float b) {
    unsigned r;
    asm("v_cvt_pk_bf16_f32 %0, %1, %2" : "=v"(r) : "v"(a), "v"(b));
    return r;
}
// native hardware 2^x — single v_exp_f32 (exp2f libcall is the precise OCML
// path: ~10 VALU/elem, measured +30us on attn in round 10)
__device__ __forceinline__ float fexp2(float x) {
    float r;
    asm("v_exp_f32 %0, %1" : "=v"(r) : "v"(x));
    return r;
}

// ---------------- fp32 -> bf16 row-major convert (8 elems/thread)
__global__ __launch_bounds__(256) void k_cvt(const float* __restrict__ s, u16* __restrict__ d) {
    size_t i = ((size_t)blockIdx.x * 256 + threadIdx.x) * 8;
    float4 v0 = *(const float4*)(s + i);
    float4 v1 = *(const float4*)(s + i + 4);
    uint4 u;
    u.x = cvtpk(v0.x, v0.y);
    u.y = cvtpk(v0.z, v0.w);
    u.z = cvtpk(v1.x, v1.y);
    u.w = cvtpk(v1.z, v1.w);
    *(uint4*)(d + i) = u;
}

// ---------------- transpose of a KxN f32 weight into N x K bf16 (optional scale)
__global__ __launch_bounds__(256) void k_tsplit(const float* __restrict__ W,
                                                u16* __restrict__ Th,
                                                int K, int N, float scale) {
    __shared__ float t[32][33];
    const int k0 = blockIdx.x * 32, n0 = blockIdx.y * 32;
    const int tx = threadIdx.x & 31, ty = threadIdx.x >> 5;
#pragma unroll
    for (int i = 0; i < 4; ++i)
        t[ty + 8 * i][tx] = W[(size_t)(k0 + ty + 8 * i) * N + (n0 + tx)];
    __syncthreads();
#pragma unroll
    for (int i = 0; i < 4; ++i) {
        float v = t[tx][ty + 8 * i] * scale;
        Th[(size_t)(n0 + ty + 8 * i) * K + (k0 + tx)] = f2bf(v);
    }
}

// ---------------- GEMM: C[M x 1024] = A[M x KTOT](bf16) @ B[1024 x KTOT](bf16)^T
// 128x128 tile, BK=64, 4 waves. Double-buffered LDS, one __syncthreads per
// K-tile; prefetch t+1 right after the barrier.
// EPI: 0 = fp32 C + bias; 3 = bf16 C + bias*bscale;
//      1 = K-tile (bf16, drow-permuted rows); 2 = V-tile (V^T bf16, natural kv)
template <int KTOT, int EPI>
__global__ __launch_bounds__(256) void k_gemm(const u16* __restrict__ Ab,
                                              const u16* __restrict__ Bb,
                                              const float* __restrict__ bias,
                                              float bscale,
                                              float* __restrict__ C,
                                              u16* __restrict__ Cb) {
    __shared__ u16 sA[2][128 * 64], sB[2][128 * 64];
    const int tid = threadIdx.x;
    const int lane = tid & 63, w = tid >> 6;
    const int wm = w >> 1, wn = w & 1;
    const int g = lane >> 4, r16 = lane & 15;
    const int m0 = blockIdx.x * 128, n0 = blockIdx.y * 128;
    const int xa = r16 & 7;
    const int NT = KTOT / 64;

    const f32x4 fzero = {0.f, 0.f, 0.f, 0.f};
    f32x4 acc[4][4];
#pragma unroll
    for (int i = 0; i < 4; ++i)
#pragma unroll
        for (int j = 0; j < 4; ++j) acc[i][j] = fzero;

    // prologue: stage tile 0 into buf 0
#pragma unroll
    for (int i = 0; i < 4; ++i) {
        int slot = tid + i * 256;
        int row = slot >> 3, cs = slot & 7;
        size_t off = (size_t)(m0 + row) * (KTOT * 2) + (size_t)((cs ^ (row & 7)) << 4);
        gload16((const char*)Ab + off, (char*)&sA[0][0] + slot * 16);
        size_t boff = (size_t)(n0 + row) * (KTOT * 2) + (size_t)((cs ^ (row & 7)) << 4);
        gload16((const char*)Bb + boff, (char*)&sB[0][0] + slot * 16);
    }

    for (int kt = 0; kt < NT; ++kt) {
        const int cur = kt & 1;
        __syncthreads();   // drains vmcnt: buf[cur] ready; buf[cur^1] free
        if (kt + 1 < NT) {
#pragma unroll
            for (int i = 0; i < 4; ++i) {
                int slot = tid + i * 256;
                int row = slot >> 3, cs = slot & 7;
                size_t off = (size_t)(m0 + row) * (KTOT * 2) + (size_t)(kt + 1) * 128 +
                             (size_t)((cs ^ (row & 7)) << 4);
                gload16((const char*)Ab + off, (char*)&sA[cur ^ 1][0] + slot * 16);
                size_t boff = (size_t)(n0 + row) * (KTOT * 2) + (size_t)(kt + 1) * 128 +
                              (size_t)((cs ^ (row & 7)) << 4);
                gload16((const char*)Bb + boff, (char*)&sB[cur ^ 1][0] + slot * 16);
            }
        }
        const char* pA = (const char*)&sA[cur][0];
        const char* pB = (const char*)&sB[cur][0];
        bf16x8 ah[4][2], bh[4][2];
#pragma unroll
        for (int f = 0; f < 4; ++f)
#pragma unroll
            for (int s = 0; s < 2; ++s) {
                const int ar = wm * 64 + f * 16 + r16;
                const int br = wn * 64 + f * 16 + r16;
                const int cb = ((s * 4 + g) ^ xa) << 4;
                ah[f][s] = *(const bf16x8*)(pA + ar * 128 + cb);
                bh[f][s] = *(const bf16x8*)(pB + br * 128 + cb);
            }
        __builtin_amdgcn_s_setprio(1);
#pragma unroll
        for (int s = 0; s < 2; ++s)
#pragma unroll
            for (int fm = 0; fm < 4; ++fm)
#pragma unroll
                for (int fn = 0; fn < 4; ++fn)
                    acc[fm][fn] = mfma_bf16(ah[fm][s], bh[fn][s], acc[fm][fn]);
        __builtin_amdgcn_s_setprio(0);
    }

#pragma unroll
    for (int fn = 0; fn < 4; ++fn) {
        const int col = n0 + wn * 64 + fn * 16 + r16;
        const float bv = bias[col] * bscale;
        const int h = col >> 6, dh = col & 63;
#pragma unroll
        for (int fm = 0; fm < 4; ++fm)
#pragma unroll
            for (int r = 0; r < 4; ++r) {
                const int row = m0 + wm * 64 + fm * 16 + g * 4 + r;
                const float v = acc[fm][fn][r] + bv;
                if constexpr (EPI == 0) {
                    C[(size_t)row * 1024 + col] = v;
                } else if constexpr (EPI == 3) {
                    Cb[(size_t)row * 1024 + col] = f2bf(v);
                } else {
                    const int b = row >> 11, kv = row & 2047;
                    const int t = kv >> 6, kvr = kv & 63;
                    const size_t tb = (size_t)((b * 16 + h) * 32 + t) * 8192;
                    if constexpr (EPI == 1) {
                        // K: drow-permuted rows, chunk-swizzled (round-7 verbatim)
                        const int drow = (kvr & 3) * 16 + (kvr >> 2);
                        Cb[tb + drow * 64 + (((dh >> 3) ^ (drow & 7)) << 3) + (dh & 7)] = f2bf(v);
                    } else {
                        // V^T: row dh, natural kv columns, chunk-swizzled (round-7 verbatim)
                        Cb[tb + 4096 + dh * 64 + (((kvr >> 3) ^ (dh & 7)) << 3) + (kvr & 7)] = f2bf(v);
                    }
                }
            }
    }
}

// ---------------- flash attention: round-7 structure (known good), pre-scaled
// bf16 Q (0.125*log2e baked in) + native v_exp_f32.
__global__ __launch_bounds__(256, 2) void k_attn(const u16* __restrict__ Qb,
                                                 const u16* __restrict__ KV,
                                                 u16* __restrict__ Af) {
    __shared__ u16 sKV[2][8192];      // per buf: [Kh 4096 u16][Vh 4096 u16]
    __shared__ u16 Ps[4][64][64];     // per-wave P, 128B rows, XOR-swizzled
    const int lin = blockIdx.x;
    const int swz = (lin & 7) * 64 + (lin >> 3);   // XCD-aware (512 % 8 == 0)
    const int qt = swz & 7, bh = swz >> 3;
    const int b = bh >> 4, h = bh & 15;
    const int tid = threadIdx.x, lane = tid & 63, w = tid >> 6;
    const int g = lane >> 4, r16 = lane & 15;
    const int xk = (r16 & 7) << 4;
    const int qbase = qt * 256 + w * 64;

    // Q fragments: Qb = 0.125*log2e*(x@Wq+bq) bf16 — direct loads
    bf16x8 qh[4][2];
#pragma unroll
    for (int rf = 0; rf < 4; ++rf) {
        const size_t qrow = (size_t)(b * SQ + qbase + rf * 16 + r16);
#pragma unroll
        for (int s = 0; s < 2; ++s)
            qh[rf][s] = *(const bf16x8*)&Qb[qrow * DA + h * 64 + s * 32 + g * 8];
    }

    const f32x4 fzero = {0.f, 0.f, 0.f, 0.f};
    f32x4 oacc[4][4];
    f32x4 l_run[4];
#pragma unroll
    for (int rf = 0; rf < 4; ++rf) {
        l_run[rf] = fzero;
#pragma unroll
        for (int i = 0; i < 4; ++i) oacc[rf][i] = fzero;
    }

    char* pw = (char*)&Ps[w][0][0];
    const char* gb0 = (const char*)KV + (size_t)bh * 32 * 16384;

    // prologue: stage tile 0 into buf 0
#pragma unroll
    for (int i = 0; i < 4; ++i) {
        int c = w * 4 + i;
        gload16(gb0 + c * 1024 + lane * 16, (char*)&sKV[0][0] + c * 1024);
    }

    for (int t = 0; t < SKV / 64; ++t) {
        const int cur = t & 1;
        __syncthreads();   // drains vmcnt: buf[cur] ready; buf[cur^1] safe to overwrite
        {
            const char* gnext = gb0 + (size_t)((t + 1) & 31) * 16384;
            char* lnext = (char*)&sKV[cur ^ 1][0];
#pragma unroll
            for (int i = 0; i < 4; ++i) {
                int c = w * 4 + i;
                gload16(gnext + c * 1024 + lane * 16, lnext + c * 1024);
            }
        }
        const char* smb = (const char*)&sKV[cur][0];

        // hoisted K fragments
        bf16x8 kh[4][2];
#pragma unroll
        for (int f = 0; f < 4; ++f)
#pragma unroll
            for (int s = 0; s < 2; ++s)
                kh[f][s] = *(const bf16x8*)(smb + (f * 16 + r16) * 128 + ((s * 64 + g * 16) ^ xk));

#pragma unroll
        for (int rf = 0; rf < 4; ++rf) {
            f32x4 sacc[4];
#pragma unroll
            for (int f = 0; f < 4; ++f) sacc[f] = fzero;
            __builtin_amdgcn_s_setprio(1);
#pragma unroll
            for (int f = 0; f < 4; ++f)
#pragma unroll
                for (int s = 0; s < 2; ++s)
                    sacc[f] = mfma_bf16(qh[rf][s], kh[f][s], sacc[f]);
            __builtin_amdgcn_s_setprio(0);
#pragma unroll
            for (int r = 0; r < 4; ++r) {
                float p0 = fexp2(sacc[0][r]);
                float p1 = fexp2(sacc[1][r]);
                float p2 = fexp2(sacc[2][r]);
                float p3 = fexp2(sacc[3][r]);
                l_run[rf][r] += (p0 + p1) + (p2 + p3);
                int prow = rf * 16 + g * 4 + r;
                uint2 pk;
                pk.x = cvtpk(p0, p1);
                pk.y = cvtpk(p2, p3);
                *(uint2*)(pw + prow * 128 + ((r16 * 8) ^ ((prow & 7) << 4))) = pk;
            }
        }

        // PV: hoisted P A-fragments, transient V fragments (bf16 V)
        bf16x8 pa[4][2];
#pragma unroll
        for (int rf = 0; rf < 4; ++rf)
#pragma unroll
            for (int s = 0; s < 2; ++s)
                pa[rf][s] = *(const bf16x8*)(pw + (rf * 16 + r16) * 128 + ((s * 64 + g * 16) ^ xk));
#pragma unroll
        for (int fd = 0; fd < 4; ++fd)
#pragma unroll
            for (int s = 0; s < 2; ++s) {
                bf16x8 vh = *(const bf16x8*)(smb + 8192 + (fd * 16 + r16) * 128 + ((s * 64 + g * 16) ^ xk));
                __builtin_amdgcn_s_setprio(1);
#pragma unroll
                for (int rf = 0; rf < 4; ++rf)
                    oacc[rf][fd] = mfma_bf16(pa[rf][s], vh, oacc[rf][fd]);
                __builtin_amdgcn_s_setprio(0);
            }
    }

    // final cross-lane reduce of l (sum over the 16 lanes sharing each row)
#pragma unroll
    for (int rf = 0; rf < 4; ++rf)
#pragma unroll
        for (int x = 1; x < 16; x <<= 1)
#pragma unroll
            for (int r = 0; r < 4; ++r) l_run[rf][r] += __shfl_xor(l_run[rf][r], x);

#pragma unroll
    for (int rf = 0; rf < 4; ++rf) {
        float linv[4];
#pragma unroll
        for (int r = 0; r < 4; ++r) linv[r] = 1.0f / l_run[rf][r];
#pragma unroll
        for (int fd = 0; fd < 4; ++fd)
#pragma unroll
            for (int r = 0; r < 4; ++r) {
                int row = qbase + rf * 16 + g * 4 + r;
                Af[(size_t)(b * SQ + row) * DA + h * 64 + fd * 16 + r16] =
                    f2bf(oacc[rf][fd][r] * linv[r]);
            }
    }
}

extern "C" void kernel_launch(void* const* d_in, const int* in_sizes, int n_in,
                              void* d_out, int out_size, void* d_ws, size_t ws_size,
                              hipStream_t stream) {
    const float* x = (const float*)d_in[0];
    const float* y = (const float*)d_in[1];
    const float* Wq = (const float*)d_in[2];
    const float* bq = (const float*)d_in[3];
    const float* Wk = (const float*)d_in[4];
    const float* bk = (const float*)d_in[5];
    const float* Wv = (const float*)d_in[6];
    const float* bv = (const float*)d_in[7];
    const float* Wo = (const float*)d_in[8];
    const float* bo = (const float*)d_in[9];
    float* out = (float*)d_out;

    char* p = (char*)d_ws;
    u16* Qb = (u16*)p; p += (size_t)MTOT * DA * 2;
    u16* Af = (u16*)p; p += (size_t)MTOT * DA * 2;
    u16* xb = (u16*)p; p += (size_t)MTOT * DE * 2;
    u16* yb = (u16*)p; p += (size_t)MTOT * DC * 2;
    u16* KV = (u16*)p; p += (size_t)64 * 32 * 8192 * 2;  // 32 MB combined K/V tiles
    u16* wq = (u16*)p; p += (size_t)DE * DA * 2;
    u16* wk = (u16*)p; p += (size_t)DC * DA * 2;
    u16* wv = (u16*)p; p += (size_t)DC * DA * 2;
    u16* wo = (u16*)p; p += (size_t)DA * DE * 2;

    const float qs = 0.125f * LOG2E;

    k_cvt<<<MTOT * DE / 2048, 256, 0, stream>>>(x, xb);
    k_cvt<<<MTOT * DC / 2048, 256, 0, stream>>>(y, yb);

    k_tsplit<<<dim3(DE / 32, DA / 32), 256, 0, stream>>>(Wq, wq, DE, DA, qs);
    k_tsplit<<<dim3(DC / 32, DA / 32), 256, 0, stream>>>(Wk, wk, DC, DA, 1.0f);
    k_tsplit<<<dim3(DC / 32, DA / 32), 256, 0, stream>>>(Wv, wv, DC, DA, 1.0f);
    k_tsplit<<<dim3(DA / 32, DE / 32), 256, 0, stream>>>(Wo, wo, DA, DE, 1.0f);

    k_gemm<DE, 3><<<dim3(MTOT / 128, DA / 128), 256, 0, stream>>>(xb, wq, bq, qs, nullptr, Qb);
    k_gemm<DC, 1><<<dim3(MTOT / 128, DA / 128), 256, 0, stream>>>(yb, wk, bk, 1.0f, nullptr, KV);
    k_gemm<DC, 2><<<dim3(MTOT / 128, DA / 128), 256, 0, stream>>>(yb, wv, bv, 1.0f, nullptr, KV);

    k_attn<<<dim3(512), 256, 0, stream>>>(Qb, KV, Af);

    k_gemm<DA, 0><<<dim3(MTOT / 128, DE / 128), 256, 0, stream>>>(Af, wo, bo, 1.0f, out, nullptr);
}